// Round 8
// baseline (337.988 us; speedup 1.0000x reference)
//
#include <hip/hip_runtime.h>
#include <hip/hip_bf16.h>

#define D 128          // D_IN == D_OUT == 128
#define BROWS 128      // nodes per coarse bucket
#define BSHIFT 7       // log2(BROWS)
#define BIN_CHUNK 8192 // edges per binning block
#define SORT_CAP 6144  // max edges sorted in LDS (mean ~4092, sigma ~64)

typedef __attribute__((ext_vector_type(8))) short short8;   // 8 bf16 (4 VGPR)
typedef __attribute__((ext_vector_type(4))) float f32x4;    // MFMA acc

static __device__ inline unsigned short f2bf(float x) {
    unsigned int u = __float_as_uint(x);
    return (unsigned short)((u + 0x7FFFu + ((u >> 16) & 1u)) >> 16);  // RNE
}
static __device__ inline float bf2f(unsigned int h16) {
    return __uint_as_float(h16 << 16);
}

// ---------------------------------------------------------------------------
// S = X @ W via v_mfma_f32_16x16x32_bf16. Block: 64 rows x 128 cols, K=128 in
// one LDS pass. Xs: bf16 [64][128] row-major, 16B-XOR swizzle (T2) per row;
// Wt: bf16 [128][128] n-major (transposed at staging), same swizzle.
// 4 waves, each owns a 64x32 column slab -> acc[4 Mfrag][2 Nfrag] f32x4.
// A/B frags use the SAME (lanegroup,slot)->k map, so the result is invariant
// to the HW's internal k ordering; C/D map col=lane&15,row=(lane>>4)*4+reg.
// ---------------------------------------------------------------------------
__global__ __launch_bounds__(256) void gemm_mfma_kernel(const float* __restrict__ X,
                                                        const float* __restrict__ W,
                                                        unsigned short* __restrict__ Sb,
                                                        int n_rows) {
    __shared__ unsigned char smem[49152];   // [0,16K)=Xs / C-stage, [16K,48K)=Wt

    const int tid  = threadIdx.x;
    const int row0 = blockIdx.x * 64;

    // ---- stage X: 64x128 fp32 -> bf16, swizzled ----
    #pragma unroll
    for (int i = 0; i < 8; ++i) {
        int idx = tid + i * 256;            // 2048 float4 units
        int r = idx >> 5, c4 = idx & 31;
        float4 v = make_float4(0.f, 0.f, 0.f, 0.f);
        if (row0 + r < n_rows) v = ((const float4*)(X + (size_t)(row0 + r) * D))[c4];
        uint2 pk;
        pk.x = (unsigned)f2bf(v.x) | ((unsigned)f2bf(v.y) << 16);
        pk.y = (unsigned)f2bf(v.z) | ((unsigned)f2bf(v.w) << 16);
        *(uint2*)(smem + r * 256 + ((c4 * 8) ^ ((r & 7) << 4))) = pk;
    }
    // ---- stage W transposed: Wt[n][k], column-coalesced global reads ----
    #pragma unroll
    for (int i = 0; i < 8; ++i) {
        int id = tid + i * 256;             // 2048 tasks: (n, 8-k chunk)
        int n = id & 127, kc = id >> 7;     // kc in [0,16)
        unsigned pk0, pk1, pk2, pk3;
        {
            float f0 = W[(size_t)(kc * 8 + 0) * D + n];
            float f1 = W[(size_t)(kc * 8 + 1) * D + n];
            float f2 = W[(size_t)(kc * 8 + 2) * D + n];
            float f3 = W[(size_t)(kc * 8 + 3) * D + n];
            float f4 = W[(size_t)(kc * 8 + 4) * D + n];
            float f5 = W[(size_t)(kc * 8 + 5) * D + n];
            float f6 = W[(size_t)(kc * 8 + 6) * D + n];
            float f7 = W[(size_t)(kc * 8 + 7) * D + n];
            pk0 = (unsigned)f2bf(f0) | ((unsigned)f2bf(f1) << 16);
            pk1 = (unsigned)f2bf(f2) | ((unsigned)f2bf(f3) << 16);
            pk2 = (unsigned)f2bf(f4) | ((unsigned)f2bf(f5) << 16);
            pk3 = (unsigned)f2bf(f6) | ((unsigned)f2bf(f7) << 16);
        }
        *(uint4*)(smem + 16384 + n * 256 + ((kc * 16) ^ ((n & 7) << 4))) =
            make_uint4(pk0, pk1, pk2, pk3);
    }
    __syncthreads();

    const int wv  = __builtin_amdgcn_readfirstlane(tid >> 6);
    const int l15 = tid & 15;
    const int lhi = (tid & 63) >> 4;

    f32x4 acc[4][2];
    #pragma unroll
    for (int m = 0; m < 4; ++m)
        #pragma unroll
        for (int j = 0; j < 2; ++j) acc[m][j] = (f32x4){0.f, 0.f, 0.f, 0.f};

    #pragma unroll
    for (int ks = 0; ks < 4; ++ks) {        // K = 4 x 32
        const int kb = ks * 64 + lhi * 16;  // byte offset of this lane's 8 bf16
        short8 a[4], b[2];
        #pragma unroll
        for (int m = 0; m < 4; ++m) {
            int r = m * 16 + l15;
            a[m] = *(const short8*)(smem + r * 256 + (kb ^ ((r & 7) << 4)));
        }
        #pragma unroll
        for (int j = 0; j < 2; ++j) {
            int n = wv * 32 + j * 16 + l15;
            b[j] = *(const short8*)(smem + 16384 + n * 256 + (kb ^ ((n & 7) << 4)));
        }
        #pragma unroll
        for (int m = 0; m < 4; ++m)
            #pragma unroll
            for (int j = 0; j < 2; ++j)
                acc[m][j] = __builtin_amdgcn_mfma_f32_16x16x32_bf16(a[m], b[j],
                                                                   acc[m][j], 0, 0, 0);
    }
    __syncthreads();

    // ---- epilogue: C -> bf16 via LDS (reuse Xs region), coalesced store ----
    #pragma unroll
    for (int m = 0; m < 4; ++m)
        #pragma unroll
        for (int j = 0; j < 2; ++j)
            #pragma unroll
            for (int r = 0; r < 4; ++r) {
                int row = m * 16 + lhi * 4 + r;
                int col = wv * 32 + j * 16 + l15;
                *(unsigned short*)(smem + row * 256 + ((col * 2) ^ ((row & 7) << 4))) =
                    f2bf(acc[m][j][r]);
            }
    __syncthreads();
    // 64x128 bf16 tile = 1024 sixteen-byte units -> 4 iterations of 256.
    // (R6 BUG: 8 iterations read past the tile and raced into the NEXT
    //  block's Sb rows — exactly the observed half-garbage S.)
    #pragma unroll
    for (int i = 0; i < 4; ++i) {
        int idx = tid + i * 256;            // 0..1023
        int r = idx >> 4, kb = (idx & 15) * 16;
        uint4 v = *(const uint4*)(smem + r * 256 + (kb ^ ((r & 7) << 4)));
        int row = row0 + r;
        if (row < n_rows)
            *(uint4*)((unsigned char*)Sb + (size_t)row * 256 + kb) = v;
    }
}

// ---------------------------------------------------------------------------
// Per-NODE histogram (global atomics, ~32 hits/counter -> low contention).
// ---------------------------------------------------------------------------
__global__ __launch_bounds__(256) void nhist_kernel(const int* __restrict__ erow,
                                                    int* __restrict__ ncnt, int n_edges) {
    int i = blockIdx.x * blockDim.x + threadIdx.x;
    int stride = gridDim.x * blockDim.x;
    for (; i < n_edges; i += stride) atomicAdd(&ncnt[erow[i]], 1);
}

// block b: sum of ncnt[b*256 .. +255] -> bsum[b]
__global__ __launch_bounds__(256) void scan1_kernel(const int* __restrict__ ncnt,
                                                    int* __restrict__ bsum, int n) {
    int i = blockIdx.x * 256 + threadIdx.x;
    int v = (i < n) ? ncnt[i] : 0;
    #pragma unroll
    for (int d = 32; d; d >>= 1) v += __shfl_down(v, d, 64);
    __shared__ int ws[4];
    int lane = threadIdx.x & 63, w = threadIdx.x >> 6;
    if (lane == 0) ws[w] = v;
    __syncthreads();
    if (threadIdx.x == 0) bsum[blockIdx.x] = ws[0] + ws[1] + ws[2] + ws[3];
}

// single block: exclusive scan of bsum[0..nblk) in place (nblk <= 1024)
__global__ __launch_bounds__(1024) void scan2_kernel(int* __restrict__ bsum, int nblk) {
    __shared__ int s[1024];
    int tid = threadIdx.x;
    int v = (tid < nblk) ? bsum[tid] : 0;
    s[tid] = v;
    __syncthreads();
    for (int d = 1; d < 1024; d <<= 1) {
        int t = (tid >= d) ? s[tid - d] : 0;
        __syncthreads();
        s[tid] += t;
        __syncthreads();
    }
    if (tid < nblk) bsum[tid] = s[tid] - v;   // exclusive
}

// block b: exclusive scan of its 256 counts + bsum[b] -> offs; fold in the
// bucket-cursor init (curm[b] = offs[b*BROWS]) for the binning pass.
__global__ __launch_bounds__(256) void scan3_kernel(const int* __restrict__ ncnt,
                                                    const int* __restrict__ bsum,
                                                    int* __restrict__ offs,
                                                    int* __restrict__ curm, int n) {
    int i = blockIdx.x * 256 + threadIdx.x;
    int v = (i < n) ? ncnt[i] : 0;
    int lane = threadIdx.x & 63, w = threadIdx.x >> 6;
    int x = v;
    #pragma unroll
    for (int d = 1; d < 64; d <<= 1) {
        int t = __shfl_up(x, d, 64);
        if (lane >= d) x += t;
    }
    __shared__ int ws[4];
    if (lane == 63) ws[w] = x;
    __syncthreads();
    int woff = bsum[blockIdx.x];
    for (int j = 0; j < w; ++j) woff += ws[j];
    if (i < n) {
        int excl = x - v + woff;
        offs[i] = excl;
        if ((i & (BROWS - 1)) == 0) curm[i >> BSHIFT] = excl;
    }
}

// ---------------------------------------------------------------------------
// Binning: each block takes BIN_CHUNK edges, reserves one contiguous range per
// touched bucket (1 global atomic per (block,bucket)), writes densely into it.
// Packed edge: x = (localrow<<25) | col, y = weight bits.
// ---------------------------------------------------------------------------
__global__ __launch_bounds__(256) void bin_kernel(const int* __restrict__ erow,
                                                  const int* __restrict__ ecol,
                                                  const float* __restrict__ ew,
                                                  int* __restrict__ curm,
                                                  int2* __restrict__ binned,
                                                  int n_edges, int nb) {
    __shared__ int h[1024];
    __shared__ int base[1024];
    const int c0 = blockIdx.x * BIN_CHUNK;
    for (int i = threadIdx.x; i < nb; i += 256) h[i] = 0;
    __syncthreads();
    for (int k = 0; k < BIN_CHUNK; k += 256) {
        int e = c0 + k + threadIdx.x;
        if (e < n_edges) atomicAdd(&h[erow[e] >> BSHIFT], 1);
    }
    __syncthreads();
    for (int b = threadIdx.x; b < nb; b += 256) {
        int c = h[b];
        if (c) base[b] = atomicAdd(&curm[b], c);
        h[b] = 0;   // reuse as local cursor
    }
    __syncthreads();
    for (int k = 0; k < BIN_CHUNK; k += 256) {
        int e = c0 + k + threadIdx.x;
        if (e < n_edges) {
            int row = erow[e];
            int b = row >> BSHIFT;
            int pos = base[b] + atomicAdd(&h[b], 1);
            int2 p;
            p.x = (int)(((unsigned)(row & (BROWS - 1)) << 25) | (unsigned)ecol[e]);
            p.y = __float_as_int(ew[e]);
            binned[pos] = p;
        }
    }
}

// ---------------------------------------------------------------------------
// Per-bucket counting sort by local row, IN PLACE in `binned`. Cursors come
// straight from offs (no histogram pass). LDS staging, linear write-back.
// Overflow (>SORT_CAP, statistically unreachable) bounces via aux (= d_out,
// free until spmm writes it; per-bucket ranges are disjoint).
// ---------------------------------------------------------------------------
__global__ __launch_bounds__(256) void csr_sort_kernel(const int* __restrict__ offs,
                                                       int2* __restrict__ binned,
                                                       int2* __restrict__ aux,
                                                       int n_nodes, int n_edges) {
    __shared__ int  lcur[BROWS];
    __shared__ int2 staged[SORT_CAP];   // 48 KB

    const int b    = blockIdx.x;
    const int row0 = b * BROWS;
    const int tid  = threadIdx.x;
    const int bs   = offs[row0];
    const int be   = (row0 + BROWS < n_nodes) ? offs[row0 + BROWS] : n_edges;
    const int cb   = be - bs;

    if (tid < BROWS) {
        int g = (row0 + tid < n_nodes) ? offs[row0 + tid] : n_edges;
        lcur[tid] = g - bs;
    }
    __syncthreads();

    if (cb <= SORT_CAP) {
        for (int i = tid; i < cb; i += 256) {
            int2 p = binned[bs + i];
            int pos = atomicAdd(&lcur[(unsigned)p.x >> 25], 1);
            staged[pos] = make_int2(p.x & 0x1FFFFFF, p.y);
        }
        __syncthreads();
        for (int i = tid; i < cb; i += 256)
            binned[bs + i] = staged[i];
    } else {
        for (int i = tid; i < cb; i += 256) aux[bs + i] = binned[bs + i];
        __syncthreads();
        for (int i = tid; i < cb; i += 256) {
            int2 p = aux[bs + i];
            int pos = atomicAdd(&lcur[(unsigned)p.x >> 25], 1);
            binned[bs + pos] = make_int2(p.x & 0x1FFFFFF, p.y);
        }
    }
}

// ---------------------------------------------------------------------------
// CSR SpMM: one wave per node. readfirstlane makes node (and thus the edge
// stream) wave-uniform -> scalar s_loads for edges; lane l gathers the bf16x2
// at cols 2l,2l+1. 8-deep unroll keeps 8 row-gathers in flight. No atomics.
// ---------------------------------------------------------------------------
__global__ __launch_bounds__(256) void spmm_csr_kernel(const unsigned short* __restrict__ Sb,
                                                       const int* __restrict__ offs,
                                                       const int2* __restrict__ edges,
                                                       const float* __restrict__ bias,
                                                       float* __restrict__ out,
                                                       int n_nodes, int n_edges) {
    const int wv   = __builtin_amdgcn_readfirstlane(threadIdx.x >> 6);
    const int node = blockIdx.x * 4 + wv;
    const int lane = threadIdx.x & 63;
    if (node >= n_nodes) return;
    const int start = offs[node];
    const int end   = (node + 1 < n_nodes) ? offs[node + 1] : n_edges;

    const unsigned* Su = (const unsigned*)Sb;   // 64 dwords per row
    float2 b2 = ((const float2*)bias)[lane];
    float ax = b2.x, ay = b2.y;

    int e = start;
    for (; e + 7 < end; e += 8) {
        int2 p[8];
        #pragma unroll
        for (int j = 0; j < 8; ++j) p[j] = edges[e + j];
        unsigned sv[8];
        #pragma unroll
        for (int j = 0; j < 8; ++j) sv[j] = Su[(size_t)p[j].x * 64 + lane];
        #pragma unroll
        for (int j = 0; j < 8; ++j) {
            float w = __int_as_float(p[j].y);
            ax += w * bf2f(sv[j] & 0xFFFFu);
            ay += w * bf2f(sv[j] >> 16);
        }
    }
    for (; e < end; ++e) {
        int2 p = edges[e];
        unsigned s = Su[(size_t)p.x * 64 + lane];
        float w = __int_as_float(p.y);
        ax += w * bf2f(s & 0xFFFFu);
        ay += w * bf2f(s >> 16);
    }

    float2 o; o.x = ax; o.y = ay;
    ((float2*)(out + (size_t)node * D))[lane] = o;
}

// ---------------------------------------------------------------------------
// Fallback path (ws too small / too many buckets): fp32 S + output atomics.
// ---------------------------------------------------------------------------
__global__ __launch_bounds__(256) void gemm_f32_kernel(const float* __restrict__ X,
                                                       const float* __restrict__ W,
                                                       float* __restrict__ S,
                                                       int n_rows) {
    __shared__ float Ws[D * D];
    __shared__ float Xs[64 * 132];
    const int tid  = threadIdx.x;
    const int row0 = blockIdx.x * 64;
    #pragma unroll
    for (int i = 0; i < 16; ++i) {
        int idx = tid + i * 256;
        ((float4*)Ws)[idx] = ((const float4*)W)[idx];
    }
    #pragma unroll
    for (int i = 0; i < 8; ++i) {
        int idx = tid + i * 256;
        int r = idx >> 5, c4 = idx & 31;
        if (row0 + r < n_rows) {
            float4 v = ((const float4*)(X + (size_t)(row0 + r) * D))[c4];
            *((float4*)&Xs[r * 132 + c4 * 4]) = v;
        }
    }
    __syncthreads();
    const int cg = tid & 15, rg = tid >> 4;
    const int r0 = rg * 4, c0 = cg * 4, c1 = 64 + cg * 4;
    float acc[4][8];
    #pragma unroll
    for (int r = 0; r < 4; ++r)
        #pragma unroll
        for (int c = 0; c < 8; ++c) acc[r][c] = 0.f;
    #pragma unroll 4
    for (int k = 0; k < D; ++k) {
        float4 w0 = *((const float4*)&Ws[k * D + c0]);
        float4 w1 = *((const float4*)&Ws[k * D + c1]);
        #pragma unroll
        for (int r = 0; r < 4; ++r) {
            float x = Xs[(r0 + r) * 132 + k];
            acc[r][0] += x * w0.x; acc[r][1] += x * w0.y;
            acc[r][2] += x * w0.z; acc[r][3] += x * w0.w;
            acc[r][4] += x * w1.x; acc[r][5] += x * w1.y;
            acc[r][6] += x * w1.z; acc[r][7] += x * w1.w;
        }
    }
    #pragma unroll
    for (int r = 0; r < 4; ++r) {
        int row = row0 + r0 + r;
        if (row < n_rows) {
            float4 o0 = {acc[r][0], acc[r][1], acc[r][2], acc[r][3]};
            float4 o1 = {acc[r][4], acc[r][5], acc[r][6], acc[r][7]};
            ((float4*)(S + (size_t)row * D))[cg]      = o0;
            ((float4*)(S + (size_t)row * D))[16 + cg] = o1;
        }
    }
}

__global__ __launch_bounds__(256) void init_out_kernel(float* __restrict__ out,
                                                       const float* __restrict__ bias,
                                                       int total4) {
    int idx = blockIdx.x * blockDim.x + threadIdx.x;
    int stride = gridDim.x * blockDim.x;
    for (; idx < total4; idx += stride) {
        float4 b = ((const float4*)bias)[idx & 31];
        ((float4*)out)[idx] = b;
    }
}

__global__ __launch_bounds__(256) void spmm_atomic_kernel(const float* __restrict__ S,
                                                          const int* __restrict__ erow,
                                                          const int* __restrict__ ecol,
                                                          const float* __restrict__ ew,
                                                          float* __restrict__ out,
                                                          int n_edges) {
    const int lane   = threadIdx.x & 63;
    const int wave   = blockIdx.x * (blockDim.x >> 6) + (threadIdx.x >> 6);
    const int nwaves = gridDim.x * (blockDim.x >> 6);
    for (int e = wave; e < n_edges; e += nwaves) {
        int   col = ecol[e];
        int   row = erow[e];
        float w   = ew[e];
        float2 s  = *(((const float2*)(S + (size_t)col * D)) + lane);
        float* op = out + (size_t)row * D + lane * 2;
        unsafeAtomicAdd(op,     w * s.x);
        unsafeAtomicAdd(op + 1, w * s.y);
    }
}

extern "C" void kernel_launch(void* const* d_in, const int* in_sizes, int n_in,
                              void* d_out, int out_size, void* d_ws, size_t ws_size,
                              hipStream_t stream) {
    const float* X    = (const float*)d_in[0];
    const int*   erow = (const int*)  d_in[1];
    const int*   ecol = (const int*)  d_in[2];
    const float* ew   = (const float*)d_in[3];
    const float* W    = (const float*)d_in[4];
    const float* bias = (const float*)d_in[5];
    float* out = (float*)d_out;

    const int n_nodes   = in_sizes[0] / D;
    const int n_edges   = in_sizes[1];
    const int nb        = (n_nodes + BROWS - 1) / BROWS;   // 782
    const int nblk_scan = (n_nodes + 255) / 256;           // 391

    // workspace: Sb (bf16) | ncnt | offs | bsum | curm | binned
    size_t sb_bytes   = (size_t)n_nodes * D * sizeof(unsigned short); // 25.6 MB
    size_t node_bytes = ((size_t)n_nodes * sizeof(int) + 15) & ~(size_t)15;
    size_t bsum_bytes = 1024 * sizeof(int);
    size_t curm_bytes = ((size_t)nb * sizeof(int) + 15) & ~(size_t)15;
    size_t bin_bytes  = (size_t)n_edges * sizeof(int2);               // 25.6 MB
    size_t need = sb_bytes + 2 * node_bytes + bsum_bytes + curm_bytes + bin_bytes + 64;
    bool aux_ok = (size_t)out_size * sizeof(float) >= bin_bytes;

    if (ws_size >= need && nb <= 1024 && nblk_scan <= 1024 && aux_ok) {
        char* p = (char*)d_ws;
        unsigned short* Sb = (unsigned short*)p;  p += sb_bytes;
        int* ncnt = (int*)p;                      p += node_bytes;
        int* offs = (int*)p;                      p += node_bytes;
        int* bsum = (int*)p;                      p += bsum_bytes;
        int* curm = (int*)p;                      p += curm_bytes;
        p = (char*)(((uintptr_t)p + 15) & ~(uintptr_t)15);
        int2* binned = (int2*)p;

        gemm_mfma_kernel<<<(n_nodes + 63) / 64, 256, 0, stream>>>(X, W, Sb, n_nodes);
        hipMemsetAsync(ncnt, 0, (size_t)n_nodes * sizeof(int), stream);
        nhist_kernel<<<1024, 256, 0, stream>>>(erow, ncnt, n_edges);
        scan1_kernel<<<nblk_scan, 256, 0, stream>>>(ncnt, bsum, n_nodes);
        scan2_kernel<<<1, 1024, 0, stream>>>(bsum, nblk_scan);
        scan3_kernel<<<nblk_scan, 256, 0, stream>>>(ncnt, bsum, offs, curm, n_nodes);
        bin_kernel<<<(n_edges + BIN_CHUNK - 1) / BIN_CHUNK, 256, 0, stream>>>(
            erow, ecol, ew, curm, binned, n_edges, nb);
        csr_sort_kernel<<<nb, 256, 0, stream>>>(offs, binned, (int2*)out,
                                                n_nodes, n_edges);
        spmm_csr_kernel<<<(n_nodes + 3) / 4, 256, 0, stream>>>(Sb, offs, binned, bias,
                                                               out, n_nodes, n_edges);
    } else {
        float* S = (float*)d_ws;
        gemm_f32_kernel<<<(n_nodes + 63) / 64, 256, 0, stream>>>(X, W, S, n_nodes);
        init_out_kernel<<<2048, 256, 0, stream>>>(out, bias, n_nodes * (D / 4));
        spmm_atomic_kernel<<<2048, 256, 0, stream>>>(S, erow, ecol, ew, out, n_edges);
    }
}

// Round 9
// 229.357 us; speedup vs baseline: 1.4736x; 1.4736x over previous
//
#include <hip/hip_runtime.h>
#include <hip/hip_bf16.h>

#define D 128          // D_IN == D_OUT == 128
#define BROWS 128      // nodes per coarse bucket
#define BSHIFT 7       // log2(BROWS)
#define BIN_CHUNK 8192 // edges per binning block
#define SORT_CAP 6144  // max edges sorted in LDS (mean ~4092, sigma ~64)

typedef __attribute__((ext_vector_type(8))) short short8;   // 8 bf16 (4 VGPR)
typedef __attribute__((ext_vector_type(4))) float f32x4;    // MFMA acc

static __device__ inline unsigned short f2bf(float x) {
    unsigned int u = __float_as_uint(x);
    return (unsigned short)((u + 0x7FFFu + ((u >> 16) & 1u)) >> 16);  // RNE
}
static __device__ inline float bf2f(unsigned int h16) {
    return __uint_as_float(h16 << 16);
}

// ---------------------------------------------------------------------------
// S = X @ W via v_mfma_f32_16x16x32_bf16 (verified in R7). 64x128 tile, K=128
// in one LDS pass; 16B-XOR swizzled Xs/Wt; epilogue bounces C through LDS.
// ---------------------------------------------------------------------------
__global__ __launch_bounds__(256) void gemm_mfma_kernel(const float* __restrict__ X,
                                                        const float* __restrict__ W,
                                                        unsigned short* __restrict__ Sb,
                                                        int n_rows) {
    __shared__ unsigned char smem[49152];   // [0,16K)=Xs / C-stage, [16K,48K)=Wt

    const int tid  = threadIdx.x;
    const int row0 = blockIdx.x * 64;

    // ---- stage X: 64x128 fp32 -> bf16, swizzled ----
    #pragma unroll
    for (int i = 0; i < 8; ++i) {
        int idx = tid + i * 256;            // 2048 float4 units
        int r = idx >> 5, c4 = idx & 31;
        float4 v = make_float4(0.f, 0.f, 0.f, 0.f);
        if (row0 + r < n_rows) v = ((const float4*)(X + (size_t)(row0 + r) * D))[c4];
        uint2 pk;
        pk.x = (unsigned)f2bf(v.x) | ((unsigned)f2bf(v.y) << 16);
        pk.y = (unsigned)f2bf(v.z) | ((unsigned)f2bf(v.w) << 16);
        *(uint2*)(smem + r * 256 + ((c4 * 8) ^ ((r & 7) << 4))) = pk;
    }
    // ---- stage W transposed: Wt[n][k], column-coalesced global reads ----
    #pragma unroll
    for (int i = 0; i < 8; ++i) {
        int id = tid + i * 256;             // 2048 tasks: (n, 8-k chunk)
        int n = id & 127, kc = id >> 7;     // kc in [0,16)
        float f0 = W[(size_t)(kc * 8 + 0) * D + n];
        float f1 = W[(size_t)(kc * 8 + 1) * D + n];
        float f2 = W[(size_t)(kc * 8 + 2) * D + n];
        float f3 = W[(size_t)(kc * 8 + 3) * D + n];
        float f4 = W[(size_t)(kc * 8 + 4) * D + n];
        float f5 = W[(size_t)(kc * 8 + 5) * D + n];
        float f6 = W[(size_t)(kc * 8 + 6) * D + n];
        float f7 = W[(size_t)(kc * 8 + 7) * D + n];
        unsigned pk0 = (unsigned)f2bf(f0) | ((unsigned)f2bf(f1) << 16);
        unsigned pk1 = (unsigned)f2bf(f2) | ((unsigned)f2bf(f3) << 16);
        unsigned pk2 = (unsigned)f2bf(f4) | ((unsigned)f2bf(f5) << 16);
        unsigned pk3 = (unsigned)f2bf(f6) | ((unsigned)f2bf(f7) << 16);
        *(uint4*)(smem + 16384 + n * 256 + ((kc * 16) ^ ((n & 7) << 4))) =
            make_uint4(pk0, pk1, pk2, pk3);
    }
    __syncthreads();

    const int wv  = __builtin_amdgcn_readfirstlane(tid >> 6);
    const int l15 = tid & 15;
    const int lhi = (tid & 63) >> 4;

    f32x4 acc[4][2];
    #pragma unroll
    for (int m = 0; m < 4; ++m)
        #pragma unroll
        for (int j = 0; j < 2; ++j) acc[m][j] = (f32x4){0.f, 0.f, 0.f, 0.f};

    #pragma unroll
    for (int ks = 0; ks < 4; ++ks) {        // K = 4 x 32
        const int kb = ks * 64 + lhi * 16;  // byte offset of this lane's 8 bf16
        short8 a[4], b[2];
        #pragma unroll
        for (int m = 0; m < 4; ++m) {
            int r = m * 16 + l15;
            a[m] = *(const short8*)(smem + r * 256 + (kb ^ ((r & 7) << 4)));
        }
        #pragma unroll
        for (int j = 0; j < 2; ++j) {
            int n = wv * 32 + j * 16 + l15;
            b[j] = *(const short8*)(smem + 16384 + n * 256 + (kb ^ ((n & 7) << 4)));
        }
        #pragma unroll
        for (int m = 0; m < 4; ++m)
            #pragma unroll
            for (int j = 0; j < 2; ++j)
                acc[m][j] = __builtin_amdgcn_mfma_f32_16x16x32_bf16(a[m], b[j],
                                                                   acc[m][j], 0, 0, 0);
    }
    __syncthreads();

    // ---- epilogue: C -> bf16 via LDS (reuse Xs region), coalesced store ----
    #pragma unroll
    for (int m = 0; m < 4; ++m)
        #pragma unroll
        for (int j = 0; j < 2; ++j)
            #pragma unroll
            for (int r = 0; r < 4; ++r) {
                int row = m * 16 + lhi * 4 + r;
                int col = wv * 32 + j * 16 + l15;
                *(unsigned short*)(smem + row * 256 + ((col * 2) ^ ((row & 7) << 4))) =
                    f2bf(acc[m][j][r]);
            }
    __syncthreads();
    // 64x128 bf16 tile = 1024 sixteen-byte units -> exactly 4 iterations.
    #pragma unroll
    for (int i = 0; i < 4; ++i) {
        int idx = tid + i * 256;            // 0..1023
        int r = idx >> 4, kb = (idx & 15) * 16;
        uint4 v = *(const uint4*)(smem + r * 256 + (kb ^ ((r & 7) << 4)));
        int row = row0 + r;
        if (row < n_rows)
            *(uint4*)((unsigned char*)Sb + (size_t)row * 256 + kb) = v;
    }
}

// ---------------------------------------------------------------------------
// Coarse bucket histogram: LDS-aggregated, one global atomic per bucket/block
// (R5's version — the per-node global-atomic hist of R6/R7 cost 130us).
// ---------------------------------------------------------------------------
__global__ __launch_bounds__(256) void bhist_kernel(const int* __restrict__ erow,
                                                    int* __restrict__ cnt,
                                                    int n_edges, int nb) {
    __shared__ int h[1024];
    for (int i = threadIdx.x; i < nb; i += 256) h[i] = 0;
    __syncthreads();
    int i = blockIdx.x * blockDim.x + threadIdx.x;
    int stride = gridDim.x * blockDim.x;
    for (; i < n_edges; i += stride) atomicAdd(&h[erow[i] >> BSHIFT], 1);
    __syncthreads();
    for (int b = threadIdx.x; b < nb; b += 256)
        if (h[b]) atomicAdd(&cnt[b], h[b]);
}

// single block: exclusive scan of cnt -> bstart (stable) and curm (cursors)
__global__ __launch_bounds__(1024) void bscan_kernel(const int* __restrict__ cnt,
                                                     int* __restrict__ bstart,
                                                     int* __restrict__ curm, int nb) {
    __shared__ int s[1024];
    int tid = threadIdx.x;
    int v = (tid < nb) ? cnt[tid] : 0;
    s[tid] = v;
    __syncthreads();
    for (int d = 1; d < 1024; d <<= 1) {
        int t = (tid >= d) ? s[tid - d] : 0;
        __syncthreads();
        s[tid] += t;
        __syncthreads();
    }
    if (tid < nb) {
        int e = s[tid] - v;   // exclusive
        bstart[tid] = e;
        curm[tid]   = e;
    }
}

// ---------------------------------------------------------------------------
// Binning: each block takes BIN_CHUNK edges, reserves one contiguous range per
// touched bucket (1 global atomic per (block,bucket)), writes densely into it.
// Packed edge: x = (localrow<<25) | col, y = weight bits.
// ---------------------------------------------------------------------------
__global__ __launch_bounds__(256) void bin_kernel(const int* __restrict__ erow,
                                                  const int* __restrict__ ecol,
                                                  const float* __restrict__ ew,
                                                  int* __restrict__ curm,
                                                  int2* __restrict__ binned,
                                                  int n_edges, int nb) {
    __shared__ int h[1024];
    __shared__ int base[1024];
    const int c0 = blockIdx.x * BIN_CHUNK;
    for (int i = threadIdx.x; i < nb; i += 256) h[i] = 0;
    __syncthreads();
    for (int k = 0; k < BIN_CHUNK; k += 256) {
        int e = c0 + k + threadIdx.x;
        if (e < n_edges) atomicAdd(&h[erow[e] >> BSHIFT], 1);
    }
    __syncthreads();
    for (int b = threadIdx.x; b < nb; b += 256) {
        int c = h[b];
        if (c) base[b] = atomicAdd(&curm[b], c);
        h[b] = 0;   // reuse as local cursor
    }
    __syncthreads();
    for (int k = 0; k < BIN_CHUNK; k += 256) {
        int e = c0 + k + threadIdx.x;
        if (e < n_edges) {
            int row = erow[e];
            int b = row >> BSHIFT;
            int pos = base[b] + atomicAdd(&h[b], 1);
            int2 p;
            p.x = (int)(((unsigned)(row & (BROWS - 1)) << 25) | (unsigned)ecol[e]);
            p.y = __float_as_int(ew[e]);
            binned[pos] = p;
        }
    }
}

// ---------------------------------------------------------------------------
// Per-bucket counting sort by local row, IN PLACE in `binned` (LDS hist +
// scan + staged scatter, linear write-back). Emits per-node CSR offsets.
// Overflow (>SORT_CAP, statistically unreachable) bounces via aux (= d_out,
// free until spmm writes it; per-bucket ranges are disjoint).
// ---------------------------------------------------------------------------
__global__ __launch_bounds__(256) void csr_sort_kernel(const int* __restrict__ cnt,
                                                       const int* __restrict__ bstart,
                                                       int2* __restrict__ binned,
                                                       int2* __restrict__ aux,
                                                       int* __restrict__ offs,
                                                       int n_nodes) {
    __shared__ int  lhist[BROWS];
    __shared__ int  lscan[BROWS];
    __shared__ int  lcur[BROWS];
    __shared__ int2 staged[SORT_CAP];   // 48 KB

    const int b    = blockIdx.x;
    const int bs   = bstart[b];
    const int cb   = cnt[b];
    const int row0 = b * BROWS;
    const int tid  = threadIdx.x;

    if (tid < BROWS) lhist[tid] = 0;
    __syncthreads();

    for (int i = tid; i < cb; i += 256)
        atomicAdd(&lhist[(unsigned)binned[bs + i].x >> 25], 1);
    __syncthreads();

    // inclusive Hillis-Steele scan over 128 bins
    if (tid < BROWS) lscan[tid] = lhist[tid];
    __syncthreads();
    for (int d = 1; d < BROWS; d <<= 1) {
        int t = 0;
        if (tid < BROWS && tid >= d) t = lscan[tid - d];
        __syncthreads();
        if (tid < BROWS) lscan[tid] += t;
        __syncthreads();
    }
    if (tid < BROWS) {
        int excl = lscan[tid] - lhist[tid];
        lcur[tid] = excl;
        if (row0 + tid < n_nodes) offs[row0 + tid] = bs + excl;
    }
    __syncthreads();

    if (cb <= SORT_CAP) {
        for (int i = tid; i < cb; i += 256) {
            int2 p = binned[bs + i];
            int pos = atomicAdd(&lcur[(unsigned)p.x >> 25], 1);
            staged[pos] = make_int2(p.x & 0x1FFFFFF, p.y);
        }
        __syncthreads();
        for (int i = tid; i < cb; i += 256)
            binned[bs + i] = staged[i];
    } else {
        for (int i = tid; i < cb; i += 256) aux[bs + i] = binned[bs + i];
        __syncthreads();
        for (int i = tid; i < cb; i += 256) {
            int2 p = aux[bs + i];
            int pos = atomicAdd(&lcur[(unsigned)p.x >> 25], 1);
            binned[bs + pos] = make_int2(p.x & 0x1FFFFFF, p.y);
        }
    }
}

// ---------------------------------------------------------------------------
// CSR SpMM: one wave per node; wave-uniform edge stream (readfirstlane);
// lane l gathers bf16x2 at cols 2l,2l+1; 8-deep unroll; no atomics.
// ---------------------------------------------------------------------------
__global__ __launch_bounds__(256) void spmm_csr_kernel(const unsigned short* __restrict__ Sb,
                                                       const int* __restrict__ offs,
                                                       const int2* __restrict__ edges,
                                                       const float* __restrict__ bias,
                                                       float* __restrict__ out,
                                                       int n_nodes, int n_edges) {
    const int wv   = __builtin_amdgcn_readfirstlane(threadIdx.x >> 6);
    const int node = blockIdx.x * 4 + wv;
    const int lane = threadIdx.x & 63;
    if (node >= n_nodes) return;
    const int start = offs[node];
    const int end   = (node + 1 < n_nodes) ? offs[node + 1] : n_edges;

    const unsigned* Su = (const unsigned*)Sb;   // 64 dwords per row
    float2 b2 = ((const float2*)bias)[lane];
    float ax = b2.x, ay = b2.y;

    int e = start;
    for (; e + 7 < end; e += 8) {
        int2 p[8];
        #pragma unroll
        for (int j = 0; j < 8; ++j) p[j] = edges[e + j];
        unsigned sv[8];
        #pragma unroll
        for (int j = 0; j < 8; ++j) sv[j] = Su[(size_t)p[j].x * 64 + lane];
        #pragma unroll
        for (int j = 0; j < 8; ++j) {
            float w = __int_as_float(p[j].y);
            ax += w * bf2f(sv[j] & 0xFFFFu);
            ay += w * bf2f(sv[j] >> 16);
        }
    }
    for (; e < end; ++e) {
        int2 p = edges[e];
        unsigned s = Su[(size_t)p.x * 64 + lane];
        float w = __int_as_float(p.y);
        ax += w * bf2f(s & 0xFFFFu);
        ay += w * bf2f(s >> 16);
    }

    float2 o; o.x = ax; o.y = ay;
    ((float2*)(out + (size_t)node * D))[lane] = o;
}

// ---------------------------------------------------------------------------
// Fallback path (ws too small / too many buckets): fp32 S + output atomics.
// ---------------------------------------------------------------------------
__global__ __launch_bounds__(256) void gemm_f32_kernel(const float* __restrict__ X,
                                                       const float* __restrict__ W,
                                                       float* __restrict__ S,
                                                       int n_rows) {
    __shared__ float Ws[D * D];
    __shared__ float Xs[64 * 132];
    const int tid  = threadIdx.x;
    const int row0 = blockIdx.x * 64;
    #pragma unroll
    for (int i = 0; i < 16; ++i) {
        int idx = tid + i * 256;
        ((float4*)Ws)[idx] = ((const float4*)W)[idx];
    }
    #pragma unroll
    for (int i = 0; i < 8; ++i) {
        int idx = tid + i * 256;
        int r = idx >> 5, c4 = idx & 31;
        if (row0 + r < n_rows) {
            float4 v = ((const float4*)(X + (size_t)(row0 + r) * D))[c4];
            *((float4*)&Xs[r * 132 + c4 * 4]) = v;
        }
    }
    __syncthreads();
    const int cg = tid & 15, rg = tid >> 4;
    const int r0 = rg * 4, c0 = cg * 4, c1 = 64 + cg * 4;
    float acc[4][8];
    #pragma unroll
    for (int r = 0; r < 4; ++r)
        #pragma unroll
        for (int c = 0; c < 8; ++c) acc[r][c] = 0.f;
    #pragma unroll 4
    for (int k = 0; k < D; ++k) {
        float4 w0 = *((const float4*)&Ws[k * D + c0]);
        float4 w1 = *((const float4*)&Ws[k * D + c1]);
        #pragma unroll
        for (int r = 0; r < 4; ++r) {
            float x = Xs[(r0 + r) * 132 + k];
            acc[r][0] += x * w0.x; acc[r][1] += x * w0.y;
            acc[r][2] += x * w0.z; acc[r][3] += x * w0.w;
            acc[r][4] += x * w1.x; acc[r][5] += x * w1.y;
            acc[r][6] += x * w1.z; acc[r][7] += x * w1.w;
        }
    }
    #pragma unroll
    for (int r = 0; r < 4; ++r) {
        int row = row0 + r0 + r;
        if (row < n_rows) {
            float4 o0 = {acc[r][0], acc[r][1], acc[r][2], acc[r][3]};
            float4 o1 = {acc[r][4], acc[r][5], acc[r][6], acc[r][7]};
            ((float4*)(S + (size_t)row * D))[cg]      = o0;
            ((float4*)(S + (size_t)row * D))[16 + cg] = o1;
        }
    }
}

__global__ __launch_bounds__(256) void init_out_kernel(float* __restrict__ out,
                                                       const float* __restrict__ bias,
                                                       int total4) {
    int idx = blockIdx.x * blockDim.x + threadIdx.x;
    int stride = gridDim.x * blockDim.x;
    for (; idx < total4; idx += stride) {
        float4 b = ((const float4*)bias)[idx & 31];
        ((float4*)out)[idx] = b;
    }
}

__global__ __launch_bounds__(256) void spmm_atomic_kernel(const float* __restrict__ S,
                                                          const int* __restrict__ erow,
                                                          const int* __restrict__ ecol,
                                                          const float* __restrict__ ew,
                                                          float* __restrict__ out,
                                                          int n_edges) {
    const int lane   = threadIdx.x & 63;
    const int wave   = blockIdx.x * (blockDim.x >> 6) + (threadIdx.x >> 6);
    const int nwaves = gridDim.x * (blockDim.x >> 6);
    for (int e = wave; e < n_edges; e += nwaves) {
        int   col = ecol[e];
        int   row = erow[e];
        float w   = ew[e];
        float2 s  = *(((const float2*)(S + (size_t)col * D)) + lane);
        float* op = out + (size_t)row * D + lane * 2;
        unsafeAtomicAdd(op,     w * s.x);
        unsafeAtomicAdd(op + 1, w * s.y);
    }
}

extern "C" void kernel_launch(void* const* d_in, const int* in_sizes, int n_in,
                              void* d_out, int out_size, void* d_ws, size_t ws_size,
                              hipStream_t stream) {
    const float* X    = (const float*)d_in[0];
    const int*   erow = (const int*)  d_in[1];
    const int*   ecol = (const int*)  d_in[2];
    const float* ew   = (const float*)d_in[3];
    const float* W    = (const float*)d_in[4];
    const float* bias = (const float*)d_in[5];
    float* out = (float*)d_out;

    const int n_nodes = in_sizes[0] / D;
    const int n_edges = in_sizes[1];
    const int nb      = (n_nodes + BROWS - 1) / BROWS;   // 782

    // workspace: Sb (bf16) | cnt | bstart | curm | offs | binned
    size_t sb_bytes   = (size_t)n_nodes * D * sizeof(unsigned short); // 25.6 MB
    size_t cnt_bytes  = ((size_t)nb * sizeof(int) + 15) & ~(size_t)15;
    size_t offs_bytes = ((size_t)n_nodes * sizeof(int) + 15) & ~(size_t)15;
    size_t bin_bytes  = (size_t)n_edges * sizeof(int2);               // 25.6 MB
    size_t need = sb_bytes + 3 * cnt_bytes + offs_bytes + bin_bytes + 64;
    bool aux_ok = (size_t)out_size * sizeof(float) >= bin_bytes;

    if (ws_size >= need && nb <= 1024 && aux_ok) {
        char* p = (char*)d_ws;
        unsigned short* Sb = (unsigned short*)p;  p += sb_bytes;
        int* cnt    = (int*)p;                    p += cnt_bytes;
        int* bstart = (int*)p;                    p += cnt_bytes;
        int* curm   = (int*)p;                    p += cnt_bytes;
        int* offs   = (int*)p;                    p += offs_bytes;
        p = (char*)(((uintptr_t)p + 15) & ~(uintptr_t)15);
        int2* binned = (int2*)p;

        gemm_mfma_kernel<<<(n_nodes + 63) / 64, 256, 0, stream>>>(X, W, Sb, n_nodes);
        hipMemsetAsync(cnt, 0, (size_t)nb * sizeof(int), stream);
        bhist_kernel<<<256, 256, 0, stream>>>(erow, cnt, n_edges, nb);
        bscan_kernel<<<1, 1024, 0, stream>>>(cnt, bstart, curm, nb);
        bin_kernel<<<(n_edges + BIN_CHUNK - 1) / BIN_CHUNK, 256, 0, stream>>>(
            erow, ecol, ew, curm, binned, n_edges, nb);
        csr_sort_kernel<<<nb, 256, 0, stream>>>(cnt, bstart, binned, (int2*)out,
                                                offs, n_nodes);
        spmm_csr_kernel<<<(n_nodes + 3) / 4, 256, 0, stream>>>(Sb, offs, binned, bias,
                                                               out, n_nodes, n_edges);
    } else {
        float* S = (float*)d_ws;
        gemm_f32_kernel<<<(n_nodes + 63) / 64, 256, 0, stream>>>(X, W, S, n_nodes);
        init_out_kernel<<<2048, 256, 0, stream>>>(out, bias, n_nodes * (D / 4));
        spmm_atomic_kernel<<<2048, 256, 0, stream>>>(S, erow, ecol, ew, out, n_edges);
    }
}

// Round 10
// 227.980 us; speedup vs baseline: 1.4825x; 1.0060x over previous
//
#include <hip/hip_runtime.h>
#include <hip/hip_bf16.h>

#define D 128            // D_IN == D_OUT == 128
#define BROWS 128        // nodes per coarse bucket
#define BSHIFT 7         // log2(BROWS)
#define BIN_CHUNK 16384  // edges per binning block (512 threads)
#define SORT_CAP 6144    // max edges sorted in LDS (mean ~4092, sigma ~64)

typedef __attribute__((ext_vector_type(8))) short short8;   // 8 bf16 (4 VGPR)
typedef __attribute__((ext_vector_type(4))) float f32x4;    // MFMA acc

static __device__ inline unsigned short f2bf(float x) {
    unsigned int u = __float_as_uint(x);
    return (unsigned short)((u + 0x7FFFu + ((u >> 16) & 1u)) >> 16);  // RNE
}
static __device__ inline float bf2f(unsigned int h16) {
    return __uint_as_float(h16 << 16);
}

// ---------------------------------------------------------------------------
// S = X @ W via v_mfma_f32_16x16x32_bf16 (verified R7/R8). 64x128 tile, K=128
// in one LDS pass; 16B-XOR swizzled Xs/Wt; epilogue bounces C through LDS.
// ---------------------------------------------------------------------------
__global__ __launch_bounds__(256) void gemm_mfma_kernel(const float* __restrict__ X,
                                                        const float* __restrict__ W,
                                                        unsigned short* __restrict__ Sb,
                                                        int n_rows) {
    __shared__ unsigned char smem[49152];   // [0,16K)=Xs / C-stage, [16K,48K)=Wt

    const int tid  = threadIdx.x;
    const int row0 = blockIdx.x * 64;

    #pragma unroll
    for (int i = 0; i < 8; ++i) {
        int idx = tid + i * 256;            // 2048 float4 units
        int r = idx >> 5, c4 = idx & 31;
        float4 v = make_float4(0.f, 0.f, 0.f, 0.f);
        if (row0 + r < n_rows) v = ((const float4*)(X + (size_t)(row0 + r) * D))[c4];
        uint2 pk;
        pk.x = (unsigned)f2bf(v.x) | ((unsigned)f2bf(v.y) << 16);
        pk.y = (unsigned)f2bf(v.z) | ((unsigned)f2bf(v.w) << 16);
        *(uint2*)(smem + r * 256 + ((c4 * 8) ^ ((r & 7) << 4))) = pk;
    }
    #pragma unroll
    for (int i = 0; i < 8; ++i) {
        int id = tid + i * 256;             // 2048 tasks: (n, 8-k chunk)
        int n = id & 127, kc = id >> 7;     // kc in [0,16)
        float f0 = W[(size_t)(kc * 8 + 0) * D + n];
        float f1 = W[(size_t)(kc * 8 + 1) * D + n];
        float f2 = W[(size_t)(kc * 8 + 2) * D + n];
        float f3 = W[(size_t)(kc * 8 + 3) * D + n];
        float f4 = W[(size_t)(kc * 8 + 4) * D + n];
        float f5 = W[(size_t)(kc * 8 + 5) * D + n];
        float f6 = W[(size_t)(kc * 8 + 6) * D + n];
        float f7 = W[(size_t)(kc * 8 + 7) * D + n];
        unsigned pk0 = (unsigned)f2bf(f0) | ((unsigned)f2bf(f1) << 16);
        unsigned pk1 = (unsigned)f2bf(f2) | ((unsigned)f2bf(f3) << 16);
        unsigned pk2 = (unsigned)f2bf(f4) | ((unsigned)f2bf(f5) << 16);
        unsigned pk3 = (unsigned)f2bf(f6) | ((unsigned)f2bf(f7) << 16);
        *(uint4*)(smem + 16384 + n * 256 + ((kc * 16) ^ ((n & 7) << 4))) =
            make_uint4(pk0, pk1, pk2, pk3);
    }
    __syncthreads();

    const int wv  = __builtin_amdgcn_readfirstlane(tid >> 6);
    const int l15 = tid & 15;
    const int lhi = (tid & 63) >> 4;

    f32x4 acc[4][2];
    #pragma unroll
    for (int m = 0; m < 4; ++m)
        #pragma unroll
        for (int j = 0; j < 2; ++j) acc[m][j] = (f32x4){0.f, 0.f, 0.f, 0.f};

    #pragma unroll
    for (int ks = 0; ks < 4; ++ks) {        // K = 4 x 32
        const int kb = ks * 64 + lhi * 16;
        short8 a[4], b[2];
        #pragma unroll
        for (int m = 0; m < 4; ++m) {
            int r = m * 16 + l15;
            a[m] = *(const short8*)(smem + r * 256 + (kb ^ ((r & 7) << 4)));
        }
        #pragma unroll
        for (int j = 0; j < 2; ++j) {
            int n = wv * 32 + j * 16 + l15;
            b[j] = *(const short8*)(smem + 16384 + n * 256 + (kb ^ ((n & 7) << 4)));
        }
        #pragma unroll
        for (int m = 0; m < 4; ++m)
            #pragma unroll
            for (int j = 0; j < 2; ++j)
                acc[m][j] = __builtin_amdgcn_mfma_f32_16x16x32_bf16(a[m], b[j],
                                                                   acc[m][j], 0, 0, 0);
    }
    __syncthreads();

    #pragma unroll
    for (int m = 0; m < 4; ++m)
        #pragma unroll
        for (int j = 0; j < 2; ++j)
            #pragma unroll
            for (int r = 0; r < 4; ++r) {
                int row = m * 16 + lhi * 4 + r;
                int col = wv * 32 + j * 16 + l15;
                *(unsigned short*)(smem + row * 256 + ((col * 2) ^ ((row & 7) << 4))) =
                    f2bf(acc[m][j][r]);
            }
    __syncthreads();
    // 64x128 bf16 tile = 1024 sixteen-byte units -> exactly 4 iterations.
    #pragma unroll
    for (int i = 0; i < 4; ++i) {
        int idx = tid + i * 256;            // 0..1023
        int r = idx >> 4, kb = (idx & 15) * 16;
        uint4 v = *(const uint4*)(smem + r * 256 + (kb ^ ((r & 7) << 4)));
        int row = row0 + r;
        if (row < n_rows)
            *(uint4*)((unsigned char*)Sb + (size_t)row * 256 + kb) = v;
    }
}

// ---------------------------------------------------------------------------
// Coarse bucket histogram: LDS-aggregated, one global atomic per bucket/block.
// ---------------------------------------------------------------------------
__global__ __launch_bounds__(256) void bhist_kernel(const int* __restrict__ erow,
                                                    int* __restrict__ cnt,
                                                    int n_edges, int nb) {
    __shared__ int h[1024];
    for (int i = threadIdx.x; i < nb; i += 256) h[i] = 0;
    __syncthreads();
    int i = blockIdx.x * blockDim.x + threadIdx.x;
    int stride = gridDim.x * blockDim.x;
    for (; i < n_edges; i += stride) atomicAdd(&h[erow[i] >> BSHIFT], 1);
    __syncthreads();
    for (int b = threadIdx.x; b < nb; b += 256)
        if (h[b]) atomicAdd(&cnt[b], h[b]);
}

// single block: exclusive scan of cnt -> bstart (stable) and curm (cursors)
__global__ __launch_bounds__(1024) void bscan_kernel(const int* __restrict__ cnt,
                                                     int* __restrict__ bstart,
                                                     int* __restrict__ curm, int nb) {
    __shared__ int s[1024];
    int tid = threadIdx.x;
    int v = (tid < nb) ? cnt[tid] : 0;
    s[tid] = v;
    __syncthreads();
    for (int d = 1; d < 1024; d <<= 1) {
        int t = (tid >= d) ? s[tid - d] : 0;
        __syncthreads();
        s[tid] += t;
        __syncthreads();
    }
    if (tid < nb) {
        int e = s[tid] - v;   // exclusive
        bstart[tid] = e;
        curm[tid]   = e;
    }
}

// ---------------------------------------------------------------------------
// Binning: 512-thread blocks, BIN_CHUNK=16384 edges each -> ~21-edge runs per
// (block,bucket) (~3 cache lines), halving the sub-line write thrash vs 8192.
// Packed edge: x = (localrow<<25) | col, y = weight bits.
// ---------------------------------------------------------------------------
__global__ __launch_bounds__(512) void bin_kernel(const int* __restrict__ erow,
                                                  const int* __restrict__ ecol,
                                                  const float* __restrict__ ew,
                                                  int* __restrict__ curm,
                                                  int2* __restrict__ binned,
                                                  int n_edges, int nb) {
    __shared__ int h[1024];
    __shared__ int base[1024];
    const int c0  = blockIdx.x * BIN_CHUNK;
    const int tid = threadIdx.x;
    for (int i = tid; i < nb; i += 512) h[i] = 0;
    __syncthreads();
    for (int k = 0; k < BIN_CHUNK; k += 512) {
        int e = c0 + k + tid;
        if (e < n_edges) atomicAdd(&h[erow[e] >> BSHIFT], 1);
    }
    __syncthreads();
    for (int b = tid; b < nb; b += 512) {
        int c = h[b];
        if (c) base[b] = atomicAdd(&curm[b], c);
        h[b] = 0;   // reuse as local cursor
    }
    __syncthreads();
    for (int k = 0; k < BIN_CHUNK; k += 512) {
        int e = c0 + k + tid;
        if (e < n_edges) {
            int row = erow[e];
            int b = row >> BSHIFT;
            int pos = base[b] + atomicAdd(&h[b], 1);
            int2 p;
            p.x = (int)(((unsigned)(row & (BROWS - 1)) << 25) | (unsigned)ecol[e]);
            p.y = __float_as_int(ew[e]);
            binned[pos] = p;
        }
    }
}

// ---------------------------------------------------------------------------
// Per-bucket counting sort, 2-pass: pass 1 reads binned ONCE (stage into LDS
// + LDS hist simultaneously); scan; pass 2 scatters LDS->final global slot
// (8B writes confined to the bucket's ~32KB range). Emits per-node offsets.
// Overflow (>SORT_CAP, statistically unreachable) bounces via aux (= d_out,
// free until spmm writes it; per-bucket ranges are disjoint).
// ---------------------------------------------------------------------------
__global__ __launch_bounds__(256) void csr_sort_kernel(const int* __restrict__ cnt,
                                                       const int* __restrict__ bstart,
                                                       int2* __restrict__ binned,
                                                       int2* __restrict__ aux,
                                                       int* __restrict__ offs,
                                                       int n_nodes) {
    __shared__ int  lhist[BROWS];
    __shared__ int  lscan[BROWS];
    __shared__ int  lcur[BROWS];
    __shared__ int2 staged[SORT_CAP];   // 48 KB

    const int b    = blockIdx.x;
    const int bs   = bstart[b];
    const int cb   = cnt[b];
    const int row0 = b * BROWS;
    const int tid  = threadIdx.x;

    if (tid < BROWS) lhist[tid] = 0;
    __syncthreads();

    if (cb <= SORT_CAP) {
        // pass 1: single global read -> LDS stage + LDS hist
        for (int i = tid; i < cb; i += 256) {
            int2 p = binned[bs + i];
            staged[i] = p;
            atomicAdd(&lhist[(unsigned)p.x >> 25], 1);
        }
        __syncthreads();
        // inclusive Hillis-Steele scan over 128 bins
        if (tid < BROWS) lscan[tid] = lhist[tid];
        __syncthreads();
        for (int d = 1; d < BROWS; d <<= 1) {
            int t = 0;
            if (tid < BROWS && tid >= d) t = lscan[tid - d];
            __syncthreads();
            if (tid < BROWS) lscan[tid] += t;
            __syncthreads();
        }
        if (tid < BROWS) {
            int excl = lscan[tid] - lhist[tid];
            lcur[tid] = excl;
            if (row0 + tid < n_nodes) offs[row0 + tid] = bs + excl;
        }
        __syncthreads();
        // pass 2: LDS -> final global position (writes stay within ~32KB)
        for (int i = tid; i < cb; i += 256) {
            int2 p = staged[i];
            int pos = atomicAdd(&lcur[(unsigned)p.x >> 25], 1);
            binned[bs + pos] = make_int2(p.x & 0x1FFFFFF, p.y);
        }
    } else {
        // rare overflow path: 3 global passes via aux
        for (int i = tid; i < cb; i += 256)
            atomicAdd(&lhist[(unsigned)binned[bs + i].x >> 25], 1);
        __syncthreads();
        if (tid < BROWS) lscan[tid] = lhist[tid];
        __syncthreads();
        for (int d = 1; d < BROWS; d <<= 1) {
            int t = 0;
            if (tid < BROWS && tid >= d) t = lscan[tid - d];
            __syncthreads();
            if (tid < BROWS) lscan[tid] += t;
            __syncthreads();
        }
        if (tid < BROWS) {
            int excl = lscan[tid] - lhist[tid];
            lcur[tid] = excl;
            if (row0 + tid < n_nodes) offs[row0 + tid] = bs + excl;
        }
        __syncthreads();
        for (int i = tid; i < cb; i += 256) aux[bs + i] = binned[bs + i];
        __syncthreads();
        for (int i = tid; i < cb; i += 256) {
            int2 p = aux[bs + i];
            int pos = atomicAdd(&lcur[(unsigned)p.x >> 25], 1);
            binned[bs + pos] = make_int2(p.x & 0x1FFFFFF, p.y);
        }
    }
}

// ---------------------------------------------------------------------------
// CSR SpMM: one wave per node; wave-uniform edge stream (scalar loads);
// lane l gathers bf16x2 at cols 2l,2l+1; 8-deep unroll; no atomics.
// ---------------------------------------------------------------------------
__global__ __launch_bounds__(256) void spmm_csr_kernel(const unsigned short* __restrict__ Sb,
                                                       const int* __restrict__ offs,
                                                       const int2* __restrict__ edges,
                                                       const float* __restrict__ bias,
                                                       float* __restrict__ out,
                                                       int n_nodes, int n_edges) {
    const int wv   = __builtin_amdgcn_readfirstlane(threadIdx.x >> 6);
    const int node = blockIdx.x * 4 + wv;
    const int lane = threadIdx.x & 63;
    if (node >= n_nodes) return;
    const int start = offs[node];
    const int end   = (node + 1 < n_nodes) ? offs[node + 1] : n_edges;

    const unsigned* Su = (const unsigned*)Sb;   // 64 dwords per row
    float2 b2 = ((const float2*)bias)[lane];
    float ax = b2.x, ay = b2.y;

    int e = start;
    for (; e + 7 < end; e += 8) {
        int2 p[8];
        #pragma unroll
        for (int j = 0; j < 8; ++j) p[j] = edges[e + j];
        unsigned sv[8];
        #pragma unroll
        for (int j = 0; j < 8; ++j) sv[j] = Su[(size_t)p[j].x * 64 + lane];
        #pragma unroll
        for (int j = 0; j < 8; ++j) {
            float w = __int_as_float(p[j].y);
            ax += w * bf2f(sv[j] & 0xFFFFu);
            ay += w * bf2f(sv[j] >> 16);
        }
    }
    for (; e < end; ++e) {
        int2 p = edges[e];
        unsigned s = Su[(size_t)p.x * 64 + lane];
        float w = __int_as_float(p.y);
        ax += w * bf2f(s & 0xFFFFu);
        ay += w * bf2f(s >> 16);
    }

    float2 o; o.x = ax; o.y = ay;
    ((float2*)(out + (size_t)node * D))[lane] = o;
}

// ---------------------------------------------------------------------------
// Fallback path (ws too small / too many buckets): fp32 S + output atomics.
// ---------------------------------------------------------------------------
__global__ __launch_bounds__(256) void gemm_f32_kernel(const float* __restrict__ X,
                                                       const float* __restrict__ W,
                                                       float* __restrict__ S,
                                                       int n_rows) {
    __shared__ float Ws[D * D];
    __shared__ float Xs[64 * 132];
    const int tid  = threadIdx.x;
    const int row0 = blockIdx.x * 64;
    #pragma unroll
    for (int i = 0; i < 16; ++i) {
        int idx = tid + i * 256;
        ((float4*)Ws)[idx] = ((const float4*)W)[idx];
    }
    #pragma unroll
    for (int i = 0; i < 8; ++i) {
        int idx = tid + i * 256;
        int r = idx >> 5, c4 = idx & 31;
        if (row0 + r < n_rows) {
            float4 v = ((const float4*)(X + (size_t)(row0 + r) * D))[c4];
            *((float4*)&Xs[r * 132 + c4 * 4]) = v;
        }
    }
    __syncthreads();
    const int cg = tid & 15, rg = tid >> 4;
    const int r0 = rg * 4, c0 = cg * 4, c1 = 64 + cg * 4;
    float acc[4][8];
    #pragma unroll
    for (int r = 0; r < 4; ++r)
        #pragma unroll
        for (int c = 0; c < 8; ++c) acc[r][c] = 0.f;
    #pragma unroll 4
    for (int k = 0; k < D; ++k) {
        float4 w0 = *((const float4*)&Ws[k * D + c0]);
        float4 w1 = *((const float4*)&Ws[k * D + c1]);
        #pragma unroll
        for (int r = 0; r < 4; ++r) {
            float x = Xs[(r0 + r) * 132 + k];
            acc[r][0] += x * w0.x; acc[r][1] += x * w0.y;
            acc[r][2] += x * w0.z; acc[r][3] += x * w0.w;
            acc[r][4] += x * w1.x; acc[r][5] += x * w1.y;
            acc[r][6] += x * w1.z; acc[r][7] += x * w1.w;
        }
    }
    #pragma unroll
    for (int r = 0; r < 4; ++r) {
        int row = row0 + r0 + r;
        if (row < n_rows) {
            float4 o0 = {acc[r][0], acc[r][1], acc[r][2], acc[r][3]};
            float4 o1 = {acc[r][4], acc[r][5], acc[r][6], acc[r][7]};
            ((float4*)(S + (size_t)row * D))[cg]      = o0;
            ((float4*)(S + (size_t)row * D))[16 + cg] = o1;
        }
    }
}

__global__ __launch_bounds__(256) void init_out_kernel(float* __restrict__ out,
                                                       const float* __restrict__ bias,
                                                       int total4) {
    int idx = blockIdx.x * blockDim.x + threadIdx.x;
    int stride = gridDim.x * blockDim.x;
    for (; idx < total4; idx += stride) {
        float4 b = ((const float4*)bias)[idx & 31];
        ((float4*)out)[idx] = b;
    }
}

__global__ __launch_bounds__(256) void spmm_atomic_kernel(const float* __restrict__ S,
                                                          const int* __restrict__ erow,
                                                          const int* __restrict__ ecol,
                                                          const float* __restrict__ ew,
                                                          float* __restrict__ out,
                                                          int n_edges) {
    const int lane   = threadIdx.x & 63;
    const int wave   = blockIdx.x * (blockDim.x >> 6) + (threadIdx.x >> 6);
    const int nwaves = gridDim.x * (blockDim.x >> 6);
    for (int e = wave; e < n_edges; e += nwaves) {
        int   col = ecol[e];
        int   row = erow[e];
        float w   = ew[e];
        float2 s  = *(((const float2*)(S + (size_t)col * D)) + lane);
        float* op = out + (size_t)row * D + lane * 2;
        unsafeAtomicAdd(op,     w * s.x);
        unsafeAtomicAdd(op + 1, w * s.y);
    }
}

extern "C" void kernel_launch(void* const* d_in, const int* in_sizes, int n_in,
                              void* d_out, int out_size, void* d_ws, size_t ws_size,
                              hipStream_t stream) {
    const float* X    = (const float*)d_in[0];
    const int*   erow = (const int*)  d_in[1];
    const int*   ecol = (const int*)  d_in[2];
    const float* ew   = (const float*)d_in[3];
    const float* W    = (const float*)d_in[4];
    const float* bias = (const float*)d_in[5];
    float* out = (float*)d_out;

    const int n_nodes = in_sizes[0] / D;
    const int n_edges = in_sizes[1];
    const int nb      = (n_nodes + BROWS - 1) / BROWS;   // 782

    // workspace: Sb (bf16) | cnt | bstart | curm | offs | binned
    size_t sb_bytes   = (size_t)n_nodes * D * sizeof(unsigned short); // 25.6 MB
    size_t cnt_bytes  = ((size_t)nb * sizeof(int) + 15) & ~(size_t)15;
    size_t offs_bytes = ((size_t)n_nodes * sizeof(int) + 15) & ~(size_t)15;
    size_t bin_bytes  = (size_t)n_edges * sizeof(int2);               // 25.6 MB
    size_t need = sb_bytes + 3 * cnt_bytes + offs_bytes + bin_bytes + 64;
    bool aux_ok = (size_t)out_size * sizeof(float) >= bin_bytes;

    if (ws_size >= need && nb <= 1024 && aux_ok) {
        char* p = (char*)d_ws;
        unsigned short* Sb = (unsigned short*)p;  p += sb_bytes;
        int* cnt    = (int*)p;                    p += cnt_bytes;
        int* bstart = (int*)p;                    p += cnt_bytes;
        int* curm   = (int*)p;                    p += cnt_bytes;
        int* offs   = (int*)p;                    p += offs_bytes;
        p = (char*)(((uintptr_t)p + 15) & ~(uintptr_t)15);
        int2* binned = (int2*)p;

        gemm_mfma_kernel<<<(n_nodes + 63) / 64, 256, 0, stream>>>(X, W, Sb, n_nodes);
        hipMemsetAsync(cnt, 0, (size_t)nb * sizeof(int), stream);
        bhist_kernel<<<256, 256, 0, stream>>>(erow, cnt, n_edges, nb);
        bscan_kernel<<<1, 1024, 0, stream>>>(cnt, bstart, curm, nb);
        bin_kernel<<<(n_edges + BIN_CHUNK - 1) / BIN_CHUNK, 512, 0, stream>>>(
            erow, ecol, ew, curm, binned, n_edges, nb);
        csr_sort_kernel<<<nb, 256, 0, stream>>>(cnt, bstart, binned, (int2*)out,
                                                offs, n_nodes);
        spmm_csr_kernel<<<(n_nodes + 3) / 4, 256, 0, stream>>>(Sb, offs, binned, bias,
                                                               out, n_nodes, n_edges);
    } else {
        float* S = (float*)d_ws;
        gemm_f32_kernel<<<(n_nodes + 63) / 64, 256, 0, stream>>>(X, W, S, n_nodes);
        init_out_kernel<<<2048, 256, 0, stream>>>(out, bias, n_nodes * (D / 4));
        spmm_atomic_kernel<<<2048, 256, 0, stream>>>(S, erow, ecol, ew, out, n_edges);
    }
}